// Round 1
// baseline (166.973 us; speedup 1.0000x reference)
//
#include <hip/hip_runtime.h>

#define BLOCK 256

// ---- compile-time chemistry tables ----
// COMMON_AM = [0,0,1,2]; type0 (H): avail slots {0,2}, dims 4; type1 (C): slots {0,1,2,3}, dims 10
__device__ const int SLOT_T0[4]  = {0,2,2,2};
__device__ const int IOF_T0[4]   = {0,0,1,2};
__device__ const int SLOT_T1[10] = {0,1,2,2,2,3,3,3,3,3};
__device__ const int IOF_T1[10]  = {0,0,0,1,2,0,1,2,3,4};
__device__ const int AVAIL_T0[2] = {0,2};
__device__ const int COFF_T0[2]  = {0,1};
__device__ const int AVAIL_T1[4] = {0,1,2,3};
__device__ const int COFF_T1[4]  = {0,1,2,5};
__device__ const int LSLOT[4]    = {0,0,1,2};
__device__ const int DSLOT[4]    = {1,1,3,5};
// feature offset of block b = 4*s1+s2 within the 100-dim edge feature
__device__ const int OFFTAB[16]  = {0,1,2,5,10,11,12,15,20,23,26,35,50,55,60,75};
// LDS base of cg_{l1,l2} (sizes 1,9,25,9,81,225,25,225,625; total 1225)
__device__ const int CGBASE9[9]  = {0,1,10,35,44,125,350,375,600};

#define CG_PARAMS const float* __restrict__ cg00, const float* __restrict__ cg01, const float* __restrict__ cg02, \
                  const float* __restrict__ cg10, const float* __restrict__ cg11, const float* __restrict__ cg12, \
                  const float* __restrict__ cg20, const float* __restrict__ cg21, const float* __restrict__ cg22

template<int T1, int T2, int NGROUPS, int T_E>
__launch_bounds__(BLOCK)
__global__ void ham_kernel(
    const float* __restrict__ fn, const float* __restrict__ fe,
    const float* __restrict__ S,
    const int* __restrict__ n1, const int* __restrict__ n2,
    const int* __restrict__ inv,
    const int* __restrict__ sel, int s,
    CG_PARAMS,
    float* __restrict__ out)
{
    constexpr int DIM1 = (T1 == 0) ? 4 : 10;
    constexpr int DIM2 = (T2 == 0) ? 4 : 10;
    constexpr int RC   = DIM1 * DIM2;
    constexpr int NA2  = (T2 == 0) ? 2 : 4;
    constexpr int NT   = DIM1 * NA2;      // row-tasks per edge
    constexpr int EPB  = NGROUPS * T_E;   // edges per block

    __shared__ float ldsF[EPB][2][104];   // [edge slot][0=e,1=inv(e)][100 feats, padded]
    __shared__ float lds_cg[1225];
    __shared__ int   lds_row[EPB][2];
    __shared__ int   lds_add[EPB][2];

    const int tid = threadIdx.x;

    // ---- phase 0: per-edge metadata (self-connection detection) ----
    if (tid < EPB) {
        int ib = blockIdx.x * EPB + tid;
        int e0 = (ib < s) ? sel[ib] : 0;
        int ei = inv[e0];
        int rows2[2] = {e0, ei};
        #pragma unroll
        for (int h = 0; h < 2; ++h) {
            int row = rows2[h];
            int a = n1[row], b = n2[row];
            float sx = S[3*row+0], sy = S[3*row+1], sz = S[3*row+2];
            bool selfe = (a == b) && (sx*sx + sy*sy + sz*sz < 1e-12f);
            lds_row[tid][h] = row;
            lds_add[tid][h] = selfe ? a : -1;
        }
    }
    // ---- stage all CG tensors into LDS ----
    for (int i = tid; i < 1;   i += BLOCK) lds_cg[0   + i] = cg00[i];
    for (int i = tid; i < 9;   i += BLOCK) lds_cg[1   + i] = cg01[i];
    for (int i = tid; i < 25;  i += BLOCK) lds_cg[10  + i] = cg02[i];
    for (int i = tid; i < 9;   i += BLOCK) lds_cg[35  + i] = cg10[i];
    for (int i = tid; i < 81;  i += BLOCK) lds_cg[44  + i] = cg11[i];
    for (int i = tid; i < 225; i += BLOCK) lds_cg[125 + i] = cg12[i];
    for (int i = tid; i < 25;  i += BLOCK) lds_cg[350 + i] = cg20[i];
    for (int i = tid; i < 225; i += BLOCK) lds_cg[375 + i] = cg21[i];
    for (int i = tid; i < 625; i += BLOCK) lds_cg[600 + i] = cg22[i];
    __syncthreads();

    // ---- phase 1: stage fe'[e] and fe'[inv e] rows (float4, self-add fused) ----
    for (int idx = tid; idx < EPB * 50; idx += BLOCK) {
        int p   = idx / 50;
        int rem = idx - p * 50;
        int h   = rem / 25;
        int q   = rem - h * 25;
        int row = lds_row[p][h];
        int an  = lds_add[p][h];
        float4 v = *((const float4*)(fe + (size_t)row * 100) + q);
        if (an >= 0) {
            float4 w = *((const float4*)(fn + (size_t)an * 100) + q);
            v.x += w.x; v.y += w.y; v.z += w.z; v.w += w.w;
        }
        *((float4*)&ldsF[p][h][q * 4]) = v;
    }
    __syncthreads();

    // ---- phase 2: each thread = one (block-row) task for T_E edges ----
    constexpr int NACT = NGROUPS * NT;
    if (tid < NACT) {
        const int rt = tid % NT;
        const int eg = tid / NT;
        const int r  = rt / NA2;
        const int a2 = rt % NA2;
        int s1, io;
        if (T1 == 0) { s1 = SLOT_T0[r]; io = IOF_T0[r]; }
        else         { s1 = SLOT_T1[r]; io = IOF_T1[r]; }
        int s2, c0;
        if (T2 == 0) { s2 = AVAIL_T0[a2]; c0 = COFF_T0[a2]; }
        else         { s2 = AVAIL_T1[a2]; c0 = COFF_T1[a2]; }
        const int l1 = LSLOT[s1], l2 = LSLOT[s2];
        const int d1 = DSLOT[s1], d2 = DSLOT[s2];
        const int K    = d1 * d2;
        const int off1 = OFFTAB[4*s1 + s2];
        const int off2 = OFFTAB[4*s2 + s1];
        const int cgb1 = CGBASE9[l1*3 + l2] + io * d2 * K;  // cg[i][j][k] = (i*d2+j)*K + k
        const int cgb2 = CGBASE9[l2*3 + l1] + io * K;       // cg'[j][i][k] = (j*d1+i)*K + k
        const int st2  = d1 * K;

        float acc[T_E][5];
        #pragma unroll
        for (int t = 0; t < T_E; ++t)
            #pragma unroll
            for (int j = 0; j < 5; ++j) acc[t][j] = 0.f;

        const int p0 = eg * T_E;
        // contribution 1: H_pre(t1,t2)[e][r][c0+j]
        for (int k = 0; k < K; ++k) {
            float f[T_E];
            #pragma unroll
            for (int t = 0; t < T_E; ++t) f[t] = ldsF[p0 + t][0][off1 + k];
            #pragma unroll
            for (int j = 0; j < 5; ++j) {
                if (j < d2) {
                    float w = lds_cg[cgb1 + j * K + k];
                    #pragma unroll
                    for (int t = 0; t < T_E; ++t) acc[t][j] = fmaf(f[t], w, acc[t][j]);
                }
            }
        }
        // contribution 2 (transpose term): H_pre(t2,t1)[inv e][c0+j][r]
        for (int k = 0; k < K; ++k) {
            float f[T_E];
            #pragma unroll
            for (int t = 0; t < T_E; ++t) f[t] = ldsF[p0 + t][1][off2 + k];
            #pragma unroll
            for (int j = 0; j < 5; ++j) {
                if (j < d2) {
                    float w = lds_cg[cgb2 + j * st2 + k];
                    #pragma unroll
                    for (int t = 0; t < T_E; ++t) acc[t][j] = fmaf(f[t], w, acc[t][j]);
                }
            }
        }
        const int rowbase = r * DIM2 + c0;
        #pragma unroll
        for (int t = 0; t < T_E; ++t) {
            int ib = blockIdx.x * EPB + p0 + t;
            if (ib < s) {
                float* o = out + (size_t)ib * RC + rowbase;
                #pragma unroll
                for (int j = 0; j < 5; ++j) if (j < d2) o[j] = 0.5f * acc[t][j];
            }
        }
    }
}

__global__ void g2b_kernel(const int* __restrict__ s00p, int s00,
                           const int* __restrict__ s01p, int s01,
                           const int* __restrict__ s10p, int s10,
                           const int* __restrict__ s11p, int s11,
                           float* __restrict__ og)
{
    int u = blockIdx.x * blockDim.x + threadIdx.x;
    if (u < s00) { og[s00p[u]] = (float)u; return; }  u -= s00;
    if (u < s01) { og[s01p[u]] = (float)u; return; }  u -= s01;
    if (u < s10) { og[s10p[u]] = (float)u; return; }  u -= s10;
    if (u < s11) { og[s11p[u]] = (float)u; return; }
}

#define CG_ARGS cg00, cg01, cg02, cg10, cg11, cg12, cg20, cg21, cg22

extern "C" void kernel_launch(void* const* d_in, const int* in_sizes, int n_in,
                              void* d_out, int out_size, void* d_ws, size_t ws_size,
                              hipStream_t stream)
{
    const float* fn  = (const float*)d_in[0];
    const float* fe  = (const float*)d_in[1];
    const float* S   = (const float*)d_in[2];
    const int*  eidx = (const int*)d_in[3];
    const int*  inv  = (const int*)d_in[5];
    const float* cg00 = (const float*)d_in[6];
    const float* cg01 = (const float*)d_in[7];
    const float* cg02 = (const float*)d_in[8];
    const float* cg10 = (const float*)d_in[9];
    const float* cg11 = (const float*)d_in[10];
    const float* cg12 = (const float*)d_in[11];
    const float* cg20 = (const float*)d_in[12];
    const float* cg21 = (const float*)d_in[13];
    const float* cg22 = (const float*)d_in[14];
    const int* sel00 = (const int*)d_in[15];
    const int* sel01 = (const int*)d_in[16];
    const int* sel10 = (const int*)d_in[17];
    const int* sel11 = (const int*)d_in[18];

    const int E  = in_sizes[3] / 2;
    const int* n1 = eidx;
    const int* n2 = eidx + E;
    const int s00 = in_sizes[15], s01 = in_sizes[16], s10 = in_sizes[17], s11 = in_sizes[18];

    float* out = (float*)d_out;
    float* o00 = out;
    float* o01 = o00 + (size_t)s00 * 16;
    float* o10 = o01 + (size_t)s01 * 40;
    float* o11 = o10 + (size_t)s10 * 40;
    float* og  = o11 + (size_t)s11 * 100;

    if (s00 > 0)
        ham_kernel<0,0,32,1><<<(s00 + 31) / 32, BLOCK, 0, stream>>>(fn, fe, S, n1, n2, inv, sel00, s00, CG_ARGS, o00);
    if (s01 > 0)
        ham_kernel<0,1,16,2><<<(s01 + 31) / 32, BLOCK, 0, stream>>>(fn, fe, S, n1, n2, inv, sel01, s01, CG_ARGS, o01);
    if (s10 > 0)
        ham_kernel<1,0,12,2><<<(s10 + 23) / 24, BLOCK, 0, stream>>>(fn, fe, S, n1, n2, inv, sel10, s10, CG_ARGS, o10);
    if (s11 > 0)
        ham_kernel<1,1,6,4><<<(s11 + 23) / 24, BLOCK, 0, stream>>>(fn, fe, S, n1, n2, inv, sel11, s11, CG_ARGS, o11);

    const int tot = s00 + s01 + s10 + s11;
    if (tot > 0)
        g2b_kernel<<<(tot + 255) / 256, 256, 0, stream>>>(sel00, s00, sel01, s01, sel10, s10, sel11, s11, og);
}

// Round 2
// 156.705 us; speedup vs baseline: 1.0655x; 1.0655x over previous
//
#include <hip/hip_runtime.h>

#define BLOCK 256

// ---- compile-time chemistry tables ----
// COMMON_AM = [0,0,1,2]
constexpr int LSLOTc[4]   = {0,0,1,2};           // l of each slot
constexpr int DSLOTc[4]   = {1,1,3,5};           // 2l+1 of each slot
// feature offset of block (s1,s2) within the 100-dim edge feature (row-major over slots)
constexpr int OFFTABc[16] = {0,1,2,5,10,11,12,15,20,23,26,35,50,55,60,75};
constexpr int ROFF0c[4]   = {0,0,1,0};           // row/col offset by slot, type0 (valid slots 0,2)
constexpr int ROFF1c[4]   = {0,1,2,5};           // row/col offset by slot, type1

struct CgPtrs { const float* p[9]; };            // p[l1*3+l2]
struct Desc   { int cb[14]; int s00, s01, s10, s11; };

// One (s1-slot, s2-slot) sub-block for one edge: fully unrolled, all indices compile-time.
template<int T1, int S1, int T2, int S2>
__device__ __forceinline__ void ham_block(
    const float* __restrict__ xr, const float* __restrict__ yr,
    const float* __restrict__ xn, const float* __restrict__ yn,
    bool selfx, bool selfy, const CgPtrs& cg, float* __restrict__ orow)
{
    constexpr int l1  = LSLOTc[S1], l2 = LSLOTc[S2];
    constexpr int d1  = DSLOTc[S1], d2 = DSLOTc[S2];
    constexpr int K   = d1 * d2;
    constexpr int off1 = OFFTABc[4 * S1 + S2];
    constexpr int off2 = OFFTABc[4 * S2 + S1];
    constexpr int DIM2 = T2 ? 10 : 4;
    constexpr int coff = T2 ? ROFF1c[S2] : ROFF0c[S2];

    const float* __restrict__ cgA = cg.p[l1 * 3 + l2];   // cg_{l1,l2}[i][j][k]
    const float* __restrict__ cgB = cg.p[l2 * 3 + l1];   // cg_{l2,l1}[j][i][k]

    float x[K], y[K];
    #pragma unroll
    for (int k = 0; k < K; ++k) x[k] = xr[off1 + k];
    if (selfx) {
        #pragma unroll
        for (int k = 0; k < K; ++k) x[k] += xn[off1 + k];
    }
    #pragma unroll
    for (int k = 0; k < K; ++k) y[k] = yr[off2 + k];
    if (selfy) {
        #pragma unroll
        for (int k = 0; k < K; ++k) y[k] += yn[off2 + k];
    }

    #pragma unroll
    for (int i = 0; i < d1; ++i) {
        float acc[d2];
        #pragma unroll
        for (int j = 0; j < d2; ++j) acc[j] = 0.f;
        #pragma unroll
        for (int k = 0; k < K; ++k) {
            #pragma unroll
            for (int j = 0; j < d2; ++j) {
                acc[j] = fmaf(x[k], cgA[(i * d2 + j) * K + k], acc[j]);
                acc[j] = fmaf(y[k], cgB[(j * d1 + i) * K + k], acc[j]);
            }
        }
        #pragma unroll
        for (int j = 0; j < d2; ++j)
            orow[i * DIM2 + coff + j] = 0.5f * acc[j];
    }
}

// One thread = one (edge, S1-slot) task. Uniform control flow across the wave.
template<int T1, int S1, int T2>
__device__ __forceinline__ void ham_slab(
    int ib, int s, const int* __restrict__ sel,
    const float* __restrict__ fn, const float* __restrict__ fe,
    const float* __restrict__ S, const int* __restrict__ n1,
    const int* __restrict__ n2, const int* __restrict__ inv,
    const CgPtrs& cg, float* __restrict__ o)
{
    constexpr int DIM1 = T1 ? 10 : 4;
    constexpr int DIM2 = T2 ? 10 : 4;
    constexpr int RC   = DIM1 * DIM2;
    constexpr int roff = T1 ? ROFF1c[S1] : ROFF0c[S1];

    if (ib >= s) return;
    const int e  = sel[ib];
    const int ei = inv[e];

    const int ax = n1[e],  bx = n2[e];
    const int ay = n1[ei], by = n2[ei];
    const float sx0 = S[3 * e],  sx1 = S[3 * e + 1],  sx2 = S[3 * e + 2];
    const float sy0 = S[3 * ei], sy1 = S[3 * ei + 1], sy2 = S[3 * ei + 2];
    const bool selfx = (ax == bx) && (sx0 * sx0 + sx1 * sx1 + sx2 * sx2 < 1e-12f);
    const bool selfy = (ay == by) && (sy0 * sy0 + sy1 * sy1 + sy2 * sy2 < 1e-12f);

    const float* __restrict__ xr = fe + (size_t)e  * 100;
    const float* __restrict__ yr = fe + (size_t)ei * 100;
    const float* __restrict__ xn = fn + (size_t)ax * 100;
    const float* __restrict__ yn = fn + (size_t)ay * 100;
    float* __restrict__ orow = o + (size_t)ib * RC + roff * DIM2;

    if constexpr (T2 == 0) {
        ham_block<T1, S1, T2, 0>(xr, yr, xn, yn, selfx, selfy, cg, orow);
        ham_block<T1, S1, T2, 2>(xr, yr, xn, yn, selfx, selfy, cg, orow);
    } else {
        ham_block<T1, S1, T2, 0>(xr, yr, xn, yn, selfx, selfy, cg, orow);
        ham_block<T1, S1, T2, 1>(xr, yr, xn, yn, selfx, selfy, cg, orow);
        ham_block<T1, S1, T2, 2>(xr, yr, xn, yn, selfx, selfy, cg, orow);
        ham_block<T1, S1, T2, 3>(xr, yr, xn, yn, selfx, selfy, cg, orow);
    }
}

__global__ __launch_bounds__(BLOCK) void fused_kernel(
    const float* __restrict__ fn, const float* __restrict__ fe,
    const float* __restrict__ S, const int* __restrict__ n1,
    const int* __restrict__ n2, const int* __restrict__ inv,
    const int* __restrict__ sel00, const int* __restrict__ sel01,
    const int* __restrict__ sel10, const int* __restrict__ sel11,
    CgPtrs cg, Desc d, float* __restrict__ out)
{
    float* o00 = out;
    float* o01 = o00 + (size_t)d.s00 * 16;
    float* o10 = o01 + (size_t)d.s01 * 40;
    float* o11 = o10 + (size_t)d.s10 * 40;
    float* og  = o11 + (size_t)d.s11 * 100;

    const int bid = blockIdx.x;
    const int tid = threadIdx.x;

#define SEG(i, CALL) \
    if (bid < d.cb[(i) + 1]) { int ib = (bid - d.cb[i]) * BLOCK + tid; CALL; return; }

    SEG(0,  (ham_slab<0, 0, 0>(ib, d.s00, sel00, fn, fe, S, n1, n2, inv, cg, o00)))
    SEG(1,  (ham_slab<0, 2, 0>(ib, d.s00, sel00, fn, fe, S, n1, n2, inv, cg, o00)))
    SEG(2,  (ham_slab<0, 0, 1>(ib, d.s01, sel01, fn, fe, S, n1, n2, inv, cg, o01)))
    SEG(3,  (ham_slab<0, 2, 1>(ib, d.s01, sel01, fn, fe, S, n1, n2, inv, cg, o01)))
    SEG(4,  (ham_slab<1, 0, 0>(ib, d.s10, sel10, fn, fe, S, n1, n2, inv, cg, o10)))
    SEG(5,  (ham_slab<1, 1, 0>(ib, d.s10, sel10, fn, fe, S, n1, n2, inv, cg, o10)))
    SEG(6,  (ham_slab<1, 2, 0>(ib, d.s10, sel10, fn, fe, S, n1, n2, inv, cg, o10)))
    SEG(7,  (ham_slab<1, 3, 0>(ib, d.s10, sel10, fn, fe, S, n1, n2, inv, cg, o10)))
    SEG(8,  (ham_slab<1, 0, 1>(ib, d.s11, sel11, fn, fe, S, n1, n2, inv, cg, o11)))
    SEG(9,  (ham_slab<1, 1, 1>(ib, d.s11, sel11, fn, fe, S, n1, n2, inv, cg, o11)))
    SEG(10, (ham_slab<1, 2, 1>(ib, d.s11, sel11, fn, fe, S, n1, n2, inv, cg, o11)))
    SEG(11, (ham_slab<1, 3, 1>(ib, d.s11, sel11, fn, fe, S, n1, n2, inv, cg, o11)))
    // segment 12: g2b scatter (float-encoded indices; counts < 2^24 so exact)
    {
        int u = (bid - d.cb[12]) * BLOCK + tid;
        if (u < d.s00) { og[sel00[u]] = (float)u; return; }  u -= d.s00;
        if (u < d.s01) { og[sel01[u]] = (float)u; return; }  u -= d.s01;
        if (u < d.s10) { og[sel10[u]] = (float)u; return; }  u -= d.s10;
        if (u < d.s11) { og[sel11[u]] = (float)u; return; }
    }
#undef SEG
}

extern "C" void kernel_launch(void* const* d_in, const int* in_sizes, int n_in,
                              void* d_out, int out_size, void* d_ws, size_t ws_size,
                              hipStream_t stream)
{
    const float* fn  = (const float*)d_in[0];
    const float* fe  = (const float*)d_in[1];
    const float* S   = (const float*)d_in[2];
    const int*  eidx = (const int*)d_in[3];
    const int*  inv  = (const int*)d_in[5];
    CgPtrs cg;
    for (int i = 0; i < 9; ++i) cg.p[i] = (const float*)d_in[6 + i];
    const int* sel00 = (const int*)d_in[15];
    const int* sel01 = (const int*)d_in[16];
    const int* sel10 = (const int*)d_in[17];
    const int* sel11 = (const int*)d_in[18];

    const int E   = in_sizes[3] / 2;
    const int* n1 = eidx;
    const int* n2 = eidx + E;

    Desc d;
    d.s00 = in_sizes[15]; d.s01 = in_sizes[16]; d.s10 = in_sizes[17]; d.s11 = in_sizes[18];
    const int tot = d.s00 + d.s01 + d.s10 + d.s11;

    const int counts[13] = { d.s00, d.s00, d.s01, d.s01,
                             d.s10, d.s10, d.s10, d.s10,
                             d.s11, d.s11, d.s11, d.s11, tot };
    d.cb[0] = 0;
    for (int i = 0; i < 13; ++i)
        d.cb[i + 1] = d.cb[i] + (counts[i] + BLOCK - 1) / BLOCK;

    if (d.cb[13] > 0)
        fused_kernel<<<d.cb[13], BLOCK, 0, stream>>>(
            fn, fe, S, n1, n2, inv, sel00, sel01, sel10, sel11,
            cg, d, (float*)d_out);
}